// Round 1
// baseline (7080.583 us; speedup 1.0000x reference)
//
#include <hip/hip_runtime.h>
#include <hip/hip_bf16.h>

// TextRNN: embed -> 2-layer LSTM (B=64,T=256,H=1024) -> proj to 32000, f32 out.
// Strategy:
//  P0: convert weights f32->bf16 in MFMA-B swizzled layout [(k>>3)][n][k&7]
//  P1: embedding gather -> xs bf16 [T*B, 512]
//  P2: chunked GEMM  G = xs@Wx1cat + b1cat   (f32, 64-step chunks)
//  P3: L1 recurrence: 4 batch-groups x 64 N-blocks, Wh slice in VGPRs,
//      h[t-1] staged in XOR-swizzled LDS, c in 1 VGPR/thread, per-group
//      64-block barrier per step (agent-scope acq/rel atomics)
//  P4/P5: same for layer 2 (input = hs1)
//  P6: out = hT_y @ W3 + b2  (f32 vector kernel, W3 read directly)
// ws usage ~182 MB.

typedef __attribute__((ext_vector_type(8))) short s16x8;
typedef __attribute__((ext_vector_type(4))) float f32x4;

#define N_CLASS 32000
#define EMB 512
#define HID 1024
#define BATCH 64
#define SEQ 256
#define TCHUNK 64
#define NG4 4096  // 4 gates * HID

static __device__ __forceinline__ short f2bf(float x) {
  __hip_bfloat16 h = __float2bfloat16(x);
  return *reinterpret_cast<short*>(&h);
}
static __device__ __forceinline__ float bf2f(short x) {
  __hip_bfloat16 h = *reinterpret_cast<__hip_bfloat16*>(&x);
  return __bfloat162float(h);
}

// ---- P0: weight conversion to swizzled bf16 B-layout -----------------------
// dst layout: sw[((k>>3)*4096 + n)*8 + (k&7)], n = gate*1024 + j
__global__ void k_conv_w4(const float* __restrict__ Wg, const float* __restrict__ Wi,
                          const float* __restrict__ Wf, const float* __restrict__ Wo,
                          short* __restrict__ sw, int K) {
  int i = blockIdx.x * 256 + threadIdx.x;
  int k8 = i >> 10, j = i & 1023;
  if (k8 >= (K >> 3)) return;
  const float* W = blockIdx.z == 0 ? Wg : blockIdx.z == 1 ? Wi : blockIdx.z == 2 ? Wf : Wo;
  s16x8 v;
#pragma unroll
  for (int e = 0; e < 8; ++e) v[e] = f2bf(W[(size_t)(k8 * 8 + e) * 1024 + j]);
  *(s16x8*)(sw + ((size_t)k8 * NG4 + blockIdx.z * 1024 + j) * 8) = v;
}

__global__ void k_bcat(const float* __restrict__ b0, const float* __restrict__ b1,
                       const float* __restrict__ b2, const float* __restrict__ b3,
                       float* __restrict__ dst) {
  int i = blockIdx.x * 256 + threadIdx.x;  // 4096
  const float* s = (i >> 10) == 0 ? b0 : (i >> 10) == 1 ? b1 : (i >> 10) == 2 ? b2 : b3;
  dst[i] = s[i & 1023];
}

__global__ void k_f2bf(const float* __restrict__ src, short* __restrict__ dst, int n) {
  int i = blockIdx.x * 256 + threadIdx.x;
  if (i < n) dst[i] = f2bf(src[i]);
}

// ---- P1: embedding gather --------------------------------------------------
__global__ void k_embed(const int* __restrict__ X, const float* __restrict__ C,
                        short* __restrict__ xs) {
  int r = blockIdx.x;  // r = t*64 + b
  int t = r >> 6, b = r & 63;
  int idx = X[b * SEQ + t];
  const float* src = C + (size_t)idx * EMB;
  float2 v = *(const float2*)(src + threadIdx.x * 2);
  short* dst = xs + (size_t)r * EMB + threadIdx.x * 2;
  dst[0] = f2bf(v.x);
  dst[1] = f2bf(v.y);
}

// ---- P2/P4: pre-activation GEMM  C = A @ Bsw + bias ------------------------
// A: bf16 row-major [Mrows, K]; Bsw swizzled; C f32 [Mrows, Ntot].
// Block: 256 thr = 4 waves, block tile 64 x (32*NSUB); B panel (full K) in LDS.
template <int NSUB>
__global__ __launch_bounds__(256) void k_gemm(const short* __restrict__ A,
                                              const short* __restrict__ Bsw,
                                              const float* __restrict__ bias,
                                              float* __restrict__ C, int Mrows, int K,
                                              int Ntot) {
  extern __shared__ char lds_raw[];
  short* lds = (short*)lds_raw;
  constexpr int BN = 32 * NSUB;
  int tid = threadIdx.x;
  int n0 = blockIdx.x * BN;
  int nchunks = (K / 8) * BN;
  for (int cid = tid; cid < nchunks; cid += 256) {
    int k8 = cid / BN, nl = cid % BN;
    *(s16x8*)(lds + (size_t)cid * 8) = *(const s16x8*)(Bsw + ((size_t)k8 * Ntot + n0 + nl) * 8);
  }
  __syncthreads();
  int lane = tid & 63, wid = tid >> 6;
  int l15 = lane & 15, l4 = lane >> 4;
  int ms = wid >> 1, ns = wid & 1;
  for (int m0 = blockIdx.y * 64; m0 < Mrows; m0 += gridDim.y * 64) {
    f32x4 acc[2][NSUB];
#pragma unroll
    for (int i = 0; i < 2; ++i)
#pragma unroll
      for (int j = 0; j < NSUB; ++j) acc[i][j] = (f32x4){0.f, 0.f, 0.f, 0.f};
    const short* a0p = A + (size_t)(m0 + ms * 32 + l15) * K + l4 * 8;
    const short* a1p = a0p + (size_t)16 * K;
#pragma unroll 2
    for (int kc = 0; kc < K / 32; ++kc) {
      s16x8 av0 = *(const s16x8*)(a0p + kc * 32);
      s16x8 av1 = *(const s16x8*)(a1p + kc * 32);
#pragma unroll
      for (int j = 0; j < NSUB; ++j) {
        s16x8 bv = *(const s16x8*)(lds + ((size_t)(kc * 4 + l4) * BN + ns * 16 * NSUB + j * 16 + l15) * 8);
        acc[0][j] = __builtin_amdgcn_mfma_f32_16x16x32_bf16(av0, bv, acc[0][j], 0, 0, 0);
        acc[1][j] = __builtin_amdgcn_mfma_f32_16x16x32_bf16(av1, bv, acc[1][j], 0, 0, 0);
      }
    }
#pragma unroll
    for (int i = 0; i < 2; ++i)
#pragma unroll
      for (int j = 0; j < NSUB; ++j) {
        int col = n0 + ns * 16 * NSUB + j * 16 + l15;
        float bv = bias[col];
#pragma unroll
        for (int r = 0; r < 4; ++r)
          C[(size_t)(m0 + ms * 32 + i * 16 + l4 * 4 + r) * Ntot + col] = acc[i][j][r] + bv;
      }
  }
}

// ---- P3/P5: LSTM recurrence ------------------------------------------------
// 256 blocks = 4 batch-groups (16 rows) x 64 N-slices (16 h-dims).
// Wave q (0..3) = gate q (g,i,f,o). Wh slice in 128 VGPR/lane.
// Per-group barrier per step; c lives in 1 VGPR per thread.
__global__ __launch_bounds__(256, 1) void k_recur(
    const float* __restrict__ G, const short* __restrict__ Whsw,
    const short* __restrict__ h_init, short* __restrict__ hs, float* __restrict__ c_buf,
    const float* __restrict__ c_init, int t0, int t1, unsigned* __restrict__ bar) {
  __shared__ short a_lds[16 * HID];    // 32 KB, XOR-swizzled rows
  __shared__ float gx[4][16][16];      // gate exchange
  int tid = threadIdx.x;
  int lane = tid & 63, q = tid >> 6;
  int l15 = lane & 15, l4 = lane >> 4;
  int group = blockIdx.x >> 6, nsl = blockIdx.x & 63;
  int col = q * 1024 + nsl * 16 + l15;
  s16x8 breg[32];
#pragma unroll
  for (int kc = 0; kc < 32; ++kc)
    breg[kc] = *(const s16x8*)(Whsw + ((size_t)(kc * 4 + l4) * NG4 + col) * 8);
  int b = tid >> 4, d = tid & 15;
  float c = (t0 == 0 ? c_init : c_buf)[(group * 16 + b) * HID + nsl * 16 + d];
  int srow = tid >> 4, scol = tid & 15;
  for (int t = t0; t < t1; ++t) {
    const short* hsrc =
        (t == 0 ? h_init : hs + (size_t)(t - 1) * BATCH * HID) + (size_t)group * 16 * HID;
#pragma unroll
    for (int i = 0; i < 8; ++i) {
      int cidx = scol + 16 * i;
      s16x8 v = *(const s16x8*)(hsrc + srow * HID + cidx * 8);
      int byteoff = (srow * 2048 + cidx * 16) ^ ((srow & 7) << 4);
      *(s16x8*)((char*)a_lds + byteoff) = v;
    }
    __syncthreads();
    f32x4 acc;
    const float* gp = G + ((size_t)(t - t0) * BATCH + group * 16 + l4 * 4) * NG4 + col;
#pragma unroll
    for (int r = 0; r < 4; ++r) acc[r] = gp[(size_t)r * NG4];
#pragma unroll
    for (int kc = 0; kc < 32; ++kc) {
      int byteoff = (l15 * 2048 + kc * 64 + l4 * 16) ^ ((l15 & 7) << 4);
      s16x8 a = *(const s16x8*)((const char*)a_lds + byteoff);
      acc = __builtin_amdgcn_mfma_f32_16x16x32_bf16(a, breg[kc], acc, 0, 0, 0);
    }
#pragma unroll
    for (int r = 0; r < 4; ++r) gx[q][l4 * 4 + r][l15] = acc[r];
    __syncthreads();
    float gg = tanhf(gx[0][b][d]);
    float gi = 1.f / (1.f + __expf(-gx[1][b][d]));
    float gf = 1.f / (1.f + __expf(-gx[2][b][d]));
    float go = 1.f / (1.f + __expf(-gx[3][b][d]));
    c = c * gf + gg * gi;
    float h = tanhf(c) * go;
    hs[(size_t)t * BATCH * HID + (group * 16 + b) * HID + nsl * 16 + d] = f2bf(h);
    __syncthreads();  // all h stores drained (waitcnt before s_barrier)
    if (t < t1 - 1) {
      if (tid == 0) {
        unsigned* p = bar + group * TCHUNK + (t - t0);
        __hip_atomic_fetch_add(p, 1u, __ATOMIC_RELEASE, __HIP_MEMORY_SCOPE_AGENT);
        while (__hip_atomic_load(p, __ATOMIC_ACQUIRE, __HIP_MEMORY_SCOPE_AGENT) < 64u)
          __builtin_amdgcn_s_sleep(2);
      }
      __syncthreads();
    }
  }
  c_buf[(group * 16 + b) * HID + nsl * 16 + d] = c;
}

// ---- P6: out = hT @ W3 + b2 (f32 vector) -----------------------------------
__global__ __launch_bounds__(256) void k_final(const short* __restrict__ hT,
                                               const float* __restrict__ W3,
                                               const float* __restrict__ b2,
                                               float* __restrict__ out) {
  __shared__ float hst[64][64];  // [k][b]
  int tid = threadIdx.x;
  int n = blockIdx.x * 256 + tid;
  float acc[64];
#pragma unroll
  for (int i = 0; i < 64; ++i) acc[i] = 0.f;
  int bb = tid >> 2, part = tid & 3;
  for (int kc = 0; kc < HID; kc += 64) {
    __syncthreads();
    s16x8 v0 = *(const s16x8*)(hT + bb * HID + kc + part * 16);
    s16x8 v1 = *(const s16x8*)(hT + bb * HID + kc + part * 16 + 8);
#pragma unroll
    for (int e = 0; e < 8; ++e) {
      hst[part * 16 + e][bb] = bf2f(v0[e]);
      hst[part * 16 + 8 + e][bb] = bf2f(v1[e]);
    }
    __syncthreads();
    for (int k = 0; k < 64; ++k) {
      float wv = W3[(size_t)(kc + k) * N_CLASS + n];
      const float4* hp = (const float4*)&hst[k][0];
#pragma unroll
      for (int b4 = 0; b4 < 16; ++b4) {
        float4 h4 = hp[b4];
        acc[b4 * 4 + 0] += h4.x * wv;
        acc[b4 * 4 + 1] += h4.y * wv;
        acc[b4 * 4 + 2] += h4.z * wv;
        acc[b4 * 4 + 3] += h4.w * wv;
      }
    }
  }
  float bv = b2[n];
#pragma unroll
  for (int b = 0; b < 64; ++b) out[(size_t)b * N_CLASS + n] = acc[b] + bv;
}

extern "C" void kernel_launch(void* const* d_in, const int* in_sizes, int n_in, void* d_out,
                              int out_size, void* d_ws, size_t ws_size, hipStream_t stream) {
  (void)in_sizes; (void)n_in; (void)out_size; (void)ws_size;
  const int* X = (const int*)d_in[0];
  const float* C = (const float*)d_in[1];
  const float* W1 = (const float*)d_in[2];
  const float* W_xi = (const float*)d_in[3];
  const float* W_xf = (const float*)d_in[4];
  const float* W_xo = (const float*)d_in[5];
  const float* W2 = (const float*)d_in[6];
  const float* W_hi = (const float*)d_in[7];
  const float* W_hf = (const float*)d_in[8];
  const float* W_ho = (const float*)d_in[9];
  const float* b1 = (const float*)d_in[10];
  const float* b_i = (const float*)d_in[11];
  const float* b_f = (const float*)d_in[12];
  const float* b_o = (const float*)d_in[13];
  const float* W1_y = (const float*)d_in[14];
  const float* W_xi_y = (const float*)d_in[15];
  const float* W_xf_y = (const float*)d_in[16];
  const float* W_xo_y = (const float*)d_in[17];
  const float* W2_y = (const float*)d_in[18];
  const float* W_hi_y = (const float*)d_in[19];
  const float* W_hf_y = (const float*)d_in[20];
  const float* W_ho_y = (const float*)d_in[21];
  const float* b1_y = (const float*)d_in[22];
  const float* b_i_y = (const float*)d_in[23];
  const float* b_f_y = (const float*)d_in[24];
  const float* b_o_y = (const float*)d_in[25];
  const float* W3 = (const float*)d_in[26];
  const float* b2 = (const float*)d_in[27];
  const float* h0 = (const float*)d_in[28];
  const float* c0 = (const float*)d_in[29];
  const float* h0_y = (const float*)d_in[30];
  const float* c0_y = (const float*)d_in[31];

  char* w = (char*)d_ws;
  size_t off = 0;
  auto take = [&](size_t bytes) {
    char* p = w + off;
    off += (bytes + 255) & ~(size_t)255;
    return p;
  };
  short* wx1 = (short*)take(512UL * NG4 * 2);
  short* wh1 = (short*)take(1024UL * NG4 * 2);
  short* wx2 = (short*)take(1024UL * NG4 * 2);
  short* wh2 = (short*)take(1024UL * NG4 * 2);
  short* xs = (short*)take((size_t)SEQ * BATCH * EMB * 2);
  short* hs1 = (short*)take((size_t)SEQ * BATCH * HID * 2);
  short* hs2 = (short*)take((size_t)SEQ * BATCH * HID * 2);
  float* G = (float*)take((size_t)TCHUNK * BATCH * NG4 * 4);
  float* bc1 = (float*)take(NG4 * 4);
  float* bc2 = (float*)take(NG4 * 4);
  short* h0b = (short*)take((size_t)BATCH * HID * 2);
  short* h0yb = (short*)take((size_t)BATCH * HID * 2);
  float* cb1 = (float*)take((size_t)BATCH * HID * 4);
  float* cb2 = (float*)take((size_t)BATCH * HID * 4);
  unsigned* bars = (unsigned*)take(16384);

  hipMemsetAsync(bars, 0, 16384, stream);
  k_bcat<<<16, 256, 0, stream>>>(b1, b_i, b_f, b_o, bc1);
  k_bcat<<<16, 256, 0, stream>>>(b1_y, b_i_y, b_f_y, b_o_y, bc2);
  k_f2bf<<<256, 256, 0, stream>>>(h0, h0b, BATCH * HID);
  k_f2bf<<<256, 256, 0, stream>>>(h0_y, h0yb, BATCH * HID);
  k_conv_w4<<<dim3(256, 1, 4), 256, 0, stream>>>(W1, W_xi, W_xf, W_xo, wx1, 512);
  k_conv_w4<<<dim3(512, 1, 4), 256, 0, stream>>>(W2, W_hi, W_hf, W_ho, wh1, 1024);
  k_conv_w4<<<dim3(512, 1, 4), 256, 0, stream>>>(W1_y, W_xi_y, W_xf_y, W_xo_y, wx2, 1024);
  k_conv_w4<<<dim3(512, 1, 4), 256, 0, stream>>>(W2_y, W_hi_y, W_hf_y, W_ho_y, wh2, 1024);
  k_embed<<<SEQ * BATCH, 256, 0, stream>>>(X, C, xs);

  for (int seg = 0; seg < 4; ++seg) {
    int t0 = seg * TCHUNK;
    k_gemm<2><<<dim3(64, 4), 256, 512 * 64 * 2, stream>>>(
        xs + (size_t)t0 * BATCH * EMB, wx1, bc1, G, TCHUNK * BATCH, 512, NG4);
    k_recur<<<256, 256, 0, stream>>>(G, wh1, h0b, hs1, cb1, c0, t0, t0 + TCHUNK,
                                     bars + seg * 256);
  }
  for (int seg = 0; seg < 4; ++seg) {
    int t0 = seg * TCHUNK;
    k_gemm<1><<<dim3(128, 2), 256, 1024 * 32 * 2, stream>>>(
        hs1 + (size_t)t0 * BATCH * HID, wx2, bc2, G, TCHUNK * BATCH, 1024, NG4);
    k_recur<<<256, 256, 0, stream>>>(G, wh2, h0yb, hs2, cb2, c0_y, t0, t0 + TCHUNK,
                                     bars + 1024 + seg * 256);
  }
  k_final<<<125, 256, 0, stream>>>(hs2 + (size_t)(SEQ - 1) * BATCH * HID, W3, b2,
                                   (float*)d_out);
}